// Round 7
// baseline (143.737 us; speedup 1.0000x reference)
//
#include <hip/hip_runtime.h>
#include <math.h>

#define N_NODES 10000
#define N_EDGES 320000
#define IN_DIM  128
#define HID     256
#define CAP     128      // fixed bucket capacity; Poisson(32) => overflow prob ~0

#define NB_GATES 128     // 32m x 64n tiles: 8 x 16
#define NB_FILL  313     // ceil(320000 / (256*4))
#define NB_XCVT  80

typedef __attribute__((ext_vector_type(8))) short frag_ab;
typedef __attribute__((ext_vector_type(4))) float frag_cd;

// ---------------- workspace layout (bytes) ----------------
// yb     : N_NODES*64 u32       @ 0          (2,560,000)  (aggregated y, packed bf16x2)
// G      : 256*1024 f32         @ 2,560,000  (1,048,576)
// Wev    : 256*256 f32          @ 3,608,576  (262,144)
// WcT    : 256*64 u32           @ 3,870,720  (65,536)     (Wc^T, packed bf16x2 [n][k])
// bc     : 256 f32              @ 3,936,256  (1,024)
// rs     : N_NODES f32          @ 3,937,280  (40,000)
// xb     : N_NODES*64 u32       @ 3,977,280  (2,560,000)  (dinv-scaled x, packed bf16x2)
// cursor : N_NODES i32          @ 6,537,280  (40,000)
// dinv   : N_NODES f32          @ 6,577,280  (40,000)
// bucket : N_NODES*CAP i32      @ 6,617,280  (5,120,000) -> total 11,737,280 B

__device__ __forceinline__ unsigned bf16rne(float f) {
    union { float f; unsigned u; } c; c.f = f;
    return (c.u + 0x7FFFu + ((c.u >> 16) & 1u)) >> 16;
}

// ---- K1 fused: gate GEMM (blocks 0..127) + bucket fill (128..440)
__global__ __launch_bounds__(256)
void k_prep(const int* __restrict__ ei, int* __restrict__ cursor,
            int* __restrict__ bucket, const float* __restrict__ iw,
            const float* __restrict__ wih, const float* __restrict__ whh,
            float* __restrict__ G) {
    __shared__ float smem[6144];  // 24 KB, used only by gates blocks
    if (blockIdx.x >= NB_GATES) {
        int e = ((blockIdx.x - NB_GATES) * 256 + threadIdx.x) * 4;
        if (e + 3 < N_EDGES) {
            int4 s4 = *(const int4*)&ei[e];
            int4 d4 = *(const int4*)&ei[N_EDGES + e];
            int p0 = atomicAdd(&cursor[d4.x], 1);
            if (p0 < CAP) bucket[d4.x * CAP + p0] = s4.x;
            int p1 = atomicAdd(&cursor[d4.y], 1);
            if (p1 < CAP) bucket[d4.y * CAP + p1] = s4.y;
            int p2 = atomicAdd(&cursor[d4.z], 1);
            if (p2 < CAP) bucket[d4.z * CAP + p2] = s4.z;
            int p3 = atomicAdd(&cursor[d4.w], 1);
            if (p3 < CAP) bucket[d4.w * CAP + p3] = s4.w;
        } else {
            for (int q = e; q < N_EDGES; ++q) {
                int s = ei[q];
                int d = ei[N_EDGES + q];
                int pos = atomicAdd(&cursor[d], 1);
                if (pos < CAP) bucket[d * CAP + pos] = s;
            }
        }
        return;
    }
    // gates: G[256,1024] = iw[256,256] @ (W_ih + W_hh)^T   32m x 64n tiles, 2x4 micro
    int bid = blockIdx.x;
    int m0 = (bid & 7) * 32, n0 = (bid >> 3) * 64;
    float (*aT)[32] = (float(*)[32])smem;             // aT[kk][m]  [64][32]
    float (*bS)[64] = (float(*)[64])(smem + 2048);    // bS[kk][n]  [64][64]
    int t = threadIdx.x;
    int tm = t & 15, tn = t >> 4;
    float acc[2][4] = {};
    for (int kt = 0; kt < 4; ++kt) {
        int k0 = kt * 64;
        {   // stage A: 32 rows x 16 float4
            int row = t >> 3;
            #pragma unroll
            for (int r = 0; r < 2; ++r) {
                int kq = 2 * (t & 7) + r;
                float4 av = *(const float4*)&iw[(m0 + row) * HID + k0 + 4 * kq];
                aT[4 * kq + 0][row] = av.x; aT[4 * kq + 1][row] = av.y;
                aT[4 * kq + 2][row] = av.z; aT[4 * kq + 3][row] = av.w;
            }
        }
        {   // stage B: 64 rows x 16 float4 (wih+whh)
            int row = t >> 2;
            #pragma unroll
            for (int r = 0; r < 4; ++r) {
                int kq = 4 * (t & 3) + r;
                float4 b1 = *(const float4*)&wih[(n0 + row) * HID + k0 + 4 * kq];
                float4 b2 = *(const float4*)&whh[(n0 + row) * HID + k0 + 4 * kq];
                bS[4 * kq + 0][row] = b1.x + b2.x; bS[4 * kq + 1][row] = b1.y + b2.y;
                bS[4 * kq + 2][row] = b1.z + b2.z; bS[4 * kq + 3][row] = b1.w + b2.w;
            }
        }
        __syncthreads();
        #pragma unroll 8
        for (int kk = 0; kk < 64; ++kk) {
            float2 a2 = *(const float2*)&aT[kk][2 * tm];
            float4 b4 = *(const float4*)&bS[kk][4 * tn];
            float a[2] = {a2.x, a2.y};
            float b[4] = {b4.x, b4.y, b4.z, b4.w};
            #pragma unroll
            for (int i = 0; i < 2; ++i)
                #pragma unroll
                for (int j = 0; j < 4; ++j)
                    acc[i][j] = fmaf(a[i], b[j], acc[i][j]);
        }
        __syncthreads();
    }
    #pragma unroll
    for (int i = 0; i < 2; ++i) {
        float4 o = make_float4(acc[i][0], acc[i][1], acc[i][2], acc[i][3]);
        *(float4*)&G[(m0 + 2 * tm + i) * 1024 + n0 + 4 * tn] = o;
    }
}

// ---- K2 fused: LSTM nonlinearity (0..255) + dinv LUT (256..295) + scaled x->bf16 (296..375)
__device__ __forceinline__ float sig_f(float x)  { return 1.f / (1.f + __expf(-x)); }
__device__ __forceinline__ float tanh_f(float x) { return 1.f - 2.f / (1.f + __expf(2.f * x)); }

__global__ __launch_bounds__(256)
void k_wev_dinv_xcvt(const float* __restrict__ G, const float* __restrict__ iw,
                     const float* __restrict__ b_ih, const float* __restrict__ b_hh,
                     float* __restrict__ Wev, const int* __restrict__ cursor,
                     float* __restrict__ dinv, const float* __restrict__ x,
                     unsigned* __restrict__ xb) {
    if (blockIdx.x >= 296) {
        // xb[v*64+i] = bf16(dinv[v] * x[v, 2i..2i+1]) packed; dinv recomputed (no LUT race)
        int tid = (blockIdx.x - 296) * 256 + threadIdx.x;
        const float2* x2 = (const float2*)x;
        #pragma unroll
        for (int it = 0; it < 32; ++it) {
            int idx = tid + it * (NB_XCVT * 256);
            if (idx < N_NODES * 64) {
                int v = idx >> 6;
                float dv = rsqrtf((float)(cursor[v] + 1));
                float2 val = x2[idx];
                xb[idx] = bf16rne(dv * val.x) | (bf16rne(dv * val.y) << 16);
            }
        }
        return;
    }
    if (blockIdx.x >= 256) {
        int v = (blockIdx.x - 256) * 256 + threadIdx.x;
        if (v < N_NODES) dinv[v] = rsqrtf((float)(cursor[v] + 1));
        return;
    }
    int r = blockIdx.x;
    int j = threadIdx.x;
    float gi = G[r * 1024 + 0   + j] + b_ih[0   + j] + b_hh[0   + j];
    float gf = G[r * 1024 + 256 + j] + b_ih[256 + j] + b_hh[256 + j];
    float gg = G[r * 1024 + 512 + j] + b_ih[512 + j] + b_hh[512 + j];
    float go = G[r * 1024 + 768 + j] + b_ih[768 + j] + b_hh[768 + j];
    float c  = sig_f(gf) * iw[r * HID + j] + sig_f(gi) * tanh_f(gg);
    Wev[r * HID + j] = sig_f(go) * tanh_f(c);
}

// ---- K3 fused: Wc GEMM -> WcT bf16 (blocks 0..128) + aggregation (129..2628)
// xb rows are pre-scaled by dinv: y[v] = dv * ( sum_s xb'[s] + xb'[v] )
__global__ __launch_bounds__(256)
void k_wc_agg(const unsigned* __restrict__ xb, const int* __restrict__ bucket,
              const int* __restrict__ cursor, const float* __restrict__ dinv,
              unsigned* __restrict__ yb, float* __restrict__ rs,
              const float* __restrict__ Wp, const float* __restrict__ bp,
              const float* __restrict__ Wev, unsigned* __restrict__ wct,
              float* __restrict__ bc) {
    __shared__ float arow[HID];
    if (blockIdx.x < 129) {
        int a = blockIdx.x;  // 0..128 (128 = bias row)
        int j = threadIdx.x;
        const float* srcRow = (a < IN_DIM) ? &Wp[a * HID] : bp;
        arow[j] = srcRow[j];
        __syncthreads();
        float acc = 0.f;
        #pragma unroll 4
        for (int k = 0; k < HID; ++k)
            acc = fmaf(arow[k], Wev[k * HID + j], acc);
        if (a < IN_DIM)
            ((unsigned short*)wct)[j * IN_DIM + a] = (unsigned short)bf16rne(acc);
        else
            bc[j] = acc;
        return;
    }
    int wv   = threadIdx.x >> 6;
    int lane = threadIdx.x & 63;
    int v = (blockIdx.x - 129) * 4 + wv;   // < 10000
    int cntv = cursor[v];
    float dv = dinv[v];
    int cnt = cntv > CAP ? CAP : cntv;
    unsigned self = xb[v * 64 + lane];     // already dinv[v]-scaled
    union { unsigned u; float f; } c0, c1;
    c0.u = self << 16; c1.u = self & 0xFFFF0000u;
    float acc0 = c0.f, acc1 = c1.f;
    float wsum = dv;
    const int4* bkt4 = (const int4*)&bucket[v * CAP];
    int j = 0;
    for (; j + 4 <= cnt; j += 4) {
        int4 s = bkt4[j >> 2];
        float w0 = dinv[s.x], w1 = dinv[s.y], w2 = dinv[s.z], w3 = dinv[s.w];
        unsigned r0 = xb[s.x * 64 + lane];
        unsigned r1 = xb[s.y * 64 + lane];
        unsigned r2 = xb[s.z * 64 + lane];
        unsigned r3 = xb[s.w * 64 + lane];
        union { unsigned u; float f; } a0, a1;
        a0.u = r0 << 16; a1.u = r0 & 0xFFFF0000u; acc0 += a0.f; acc1 += a1.f;
        a0.u = r1 << 16; a1.u = r1 & 0xFFFF0000u; acc0 += a0.f; acc1 += a1.f;
        a0.u = r2 << 16; a1.u = r2 & 0xFFFF0000u; acc0 += a0.f; acc1 += a1.f;
        a0.u = r3 << 16; a1.u = r3 & 0xFFFF0000u; acc0 += a0.f; acc1 += a1.f;
        wsum += w0 + w1 + w2 + w3;
    }
    for (; j < cnt; ++j) {
        int s = ((const int*)bkt4)[j];
        wsum += dinv[s];
        unsigned r = xb[s * 64 + lane];
        union { unsigned u; float f; } a0, a1;
        a0.u = r << 16; a1.u = r & 0xFFFF0000u; acc0 += a0.f; acc1 += a1.f;
    }
    yb[v * 64 + lane] = bf16rne(dv * acc0) | (bf16rne(dv * acc1) << 16);
    if (lane == 0) rs[v] = dv * wsum;
}

// ---- K4: out[10000,256] = yb @ WcT^T + rs*bc + b_gcn   (bf16 MFMA, 32 rows/block)
// wave w handles n in [w*64, w*64+64); b-frags reused across 2 m-tiles.
// Epilogue: LDS transpose -> 256-B-contiguous float4 stores.
__global__ __launch_bounds__(256)
void k_out(const unsigned* __restrict__ yb, const unsigned* __restrict__ wct,
           const float* __restrict__ bc, const float* __restrict__ rs,
           const float* __restrict__ b_gcn, float* __restrict__ out) {
    __shared__ float sm[32][260];   // stride 260: 2-way write aliasing (free)
    int m0 = blockIdx.x * 32;
    int w = threadIdx.x >> 6, lane = threadIdx.x & 63;
    int q = lane >> 4, ln = lane & 15;
    const int4* yb4  = (const int4*)yb;
    const int4* wct4 = (const int4*)wct;
    union F { int4 v; frag_ab f; };
    F a[2][4];
    #pragma unroll
    for (int mt = 0; mt < 2; ++mt)
        #pragma unroll
        for (int kc = 0; kc < 4; ++kc)
            a[mt][kc].v = yb4[(m0 + mt * 16 + ln) * 16 + kc * 4 + q];
    #pragma unroll
    for (int i = 0; i < 4; ++i) {
        int n0w = w * 64 + i * 16;
        F b[4];
        #pragma unroll
        for (int kc = 0; kc < 4; ++kc)
            b[kc].v = wct4[(n0w + ln) * 16 + kc * 4 + q];
        frag_cd acc0 = {0.f, 0.f, 0.f, 0.f};
        frag_cd acc1 = {0.f, 0.f, 0.f, 0.f};
        #pragma unroll
        for (int kc = 0; kc < 4; ++kc) {
            acc0 = __builtin_amdgcn_mfma_f32_16x16x32_bf16(a[0][kc].f, b[kc].f, acc0, 0, 0, 0);
            acc1 = __builtin_amdgcn_mfma_f32_16x16x32_bf16(a[1][kc].f, b[kc].f, acc1, 0, 0, 0);
        }
        #pragma unroll
        for (int r = 0; r < 4; ++r) {
            sm[q * 4 + r][n0w + ln]      = acc0[r];
            sm[16 + q * 4 + r][n0w + ln] = acc1[r];
        }
    }
    __syncthreads();
    int m  = threadIdx.x >> 3;   // 0..31
    int cg = threadIdx.x & 7;
    int gm = m0 + m;
    if (gm < N_NODES) {
        float rsv = rs[gm];
        #pragma unroll
        for (int c = 0; c < 8; ++c) {
            int col = c * 32 + cg * 4;
            float4 vv  = *(float4*)&sm[m][col];
            float4 bcv = *(const float4*)&bc[col];
            float4 bgv = *(const float4*)&b_gcn[col];
            float4 o;
            o.x = vv.x + rsv * bcv.x + bgv.x;
            o.y = vv.y + rsv * bcv.y + bgv.y;
            o.z = vv.z + rsv * bcv.z + bgv.z;
            o.w = vv.w + rsv * bcv.w + bgv.w;
            *(float4*)&out[gm * HID + col] = o;
        }
    }
}

extern "C" void kernel_launch(void* const* d_in, const int* in_sizes, int n_in,
                              void* d_out, int out_size, void* d_ws, size_t ws_size,
                              hipStream_t stream) {
    const float* x     = (const float*)d_in[0];
    const int*   ei    = (const int*)d_in[1];
    const float* Wp    = (const float*)d_in[2];
    const float* bp    = (const float*)d_in[3];
    const float* W_ih  = (const float*)d_in[4];
    const float* W_hh  = (const float*)d_in[5];
    const float* b_ih  = (const float*)d_in[6];
    const float* b_hh  = (const float*)d_in[7];
    const float* iw    = (const float*)d_in[8];
    const float* b_gcn = (const float*)d_in[9];
    float* out = (float*)d_out;

    char* ws = (char*)d_ws;
    unsigned* yb     = (unsigned*)(ws + 0);
    float*    G      = (float*)   (ws + 2560000);
    float*    Wev    = (float*)   (ws + 3608576);
    unsigned* wct    = (unsigned*)(ws + 3870720);
    float*    bc     = (float*)   (ws + 3936256);
    float*    rs     = (float*)   (ws + 3937280);
    unsigned* xb     = (unsigned*)(ws + 3977280);
    int*      cursor = (int*)     (ws + 6537280);
    float*    dinv   = (float*)   (ws + 6577280);
    int*      bucket = (int*)     (ws + 6617280);

    hipMemsetAsync(cursor, 0, N_NODES * sizeof(int), stream);

    // K1: gates GEMM + bucket fill
    k_prep<<<NB_GATES + NB_FILL, 256, 0, stream>>>(ei, cursor, bucket, iw, W_ih, W_hh, G);
    // K2: LSTM nonlinearity + dinv LUT + dinv-scaled x->bf16
    k_wev_dinv_xcvt<<<256 + 40 + NB_XCVT, 256, 0, stream>>>(
        G, iw, b_ih, b_hh, Wev, cursor, dinv, x, xb);
    // K3: WcT bf16 GEMM + aggregation (add-only inner loop)
    k_wc_agg<<<129 + 2500, 256, 0, stream>>>(xb, bucket, cursor, dinv, yb, rs, Wp, bp, Wev, wct, bc);
    // K4: final GEMM via bf16 MFMA + LDS-transposed epilogue
    k_out<<<313, 256, 0, stream>>>(yb, wct, bc, rs, b_gcn, out);
}

// Round 8
// 132.081 us; speedup vs baseline: 1.0882x; 1.0882x over previous
//
#include <hip/hip_runtime.h>
#include <math.h>

#define N_NODES 10000
#define N_EDGES 320000
#define IN_DIM  128
#define HID     256
#define CAP     128      // fixed bucket capacity; Poisson(32) => overflow prob ~0

#define NB_GATES 128     // 32m x 64n tiles: 8 x 16
#define NB_FILL  313     // ceil(320000 / (256*4))
#define NB_XCVT  640     // wide: 4 iters/block, latency overlapped

typedef __attribute__((ext_vector_type(8))) short frag_ab;
typedef __attribute__((ext_vector_type(4))) float frag_cd;

// ---------------- workspace layout (bytes) ----------------
// yb     : N_NODES*64 u32       @ 0          (2,560,000)  (aggregated y, packed bf16x2)
// G      : 256*1024 f32         @ 2,560,000  (1,048,576)
// Wev    : 256*256 f32          @ 3,608,576  (262,144)
// WcT    : 256*64 u32           @ 3,870,720  (65,536)     (Wc^T, packed bf16x2 [n][k])
// bc     : 256 f32              @ 3,936,256  (1,024)
// rs     : N_NODES f32          @ 3,937,280  (40,000)
// xb     : N_NODES*64 u32       @ 3,977,280  (2,560,000)  (x, packed bf16x2)
// cursor : N_NODES i32          @ 6,537,280  (40,000)
// dinv   : N_NODES f32          @ 6,577,280  (40,000)
// bucket : N_NODES*CAP i32      @ 6,617,280  (5,120,000) -> total 11,737,280 B

__device__ __forceinline__ unsigned bf16rne(float f) {
    union { float f; unsigned u; } c; c.f = f;
    return (c.u + 0x7FFFu + ((c.u >> 16) & 1u)) >> 16;
}

// ---- K1 fused: gate GEMM (0..127) + bucket fill (128..440) + x->bf16 (441..1080)
__global__ __launch_bounds__(256)
void k_prep(const int* __restrict__ ei, int* __restrict__ cursor,
            int* __restrict__ bucket, const float* __restrict__ iw,
            const float* __restrict__ wih, const float* __restrict__ whh,
            float* __restrict__ G, const float* __restrict__ x,
            unsigned* __restrict__ xb) {
    __shared__ float smem[6144];  // 24 KB, used only by gates blocks
    if (blockIdx.x >= NB_GATES + NB_FILL) {
        // x -> packed bf16x2 (640,000 u32 total), 640 blocks x 4 iters
        int tid = (blockIdx.x - NB_GATES - NB_FILL) * 256 + threadIdx.x;
        const float2* x2 = (const float2*)x;
        #pragma unroll
        for (int it = 0; it < 4; ++it) {
            int idx = tid + it * (NB_XCVT * 256);
            if (idx < N_NODES * 64) {
                float2 v = x2[idx];
                xb[idx] = bf16rne(v.x) | (bf16rne(v.y) << 16);
            }
        }
        return;
    }
    if (blockIdx.x >= NB_GATES) {
        int e = ((blockIdx.x - NB_GATES) * 256 + threadIdx.x) * 4;
        if (e + 3 < N_EDGES) {
            int4 s4 = *(const int4*)&ei[e];
            int4 d4 = *(const int4*)&ei[N_EDGES + e];
            int p0 = atomicAdd(&cursor[d4.x], 1);
            if (p0 < CAP) bucket[d4.x * CAP + p0] = s4.x;
            int p1 = atomicAdd(&cursor[d4.y], 1);
            if (p1 < CAP) bucket[d4.y * CAP + p1] = s4.y;
            int p2 = atomicAdd(&cursor[d4.z], 1);
            if (p2 < CAP) bucket[d4.z * CAP + p2] = s4.z;
            int p3 = atomicAdd(&cursor[d4.w], 1);
            if (p3 < CAP) bucket[d4.w * CAP + p3] = s4.w;
        } else {
            for (int q = e; q < N_EDGES; ++q) {
                int s = ei[q];
                int d = ei[N_EDGES + q];
                int pos = atomicAdd(&cursor[d], 1);
                if (pos < CAP) bucket[d * CAP + pos] = s;
            }
        }
        return;
    }
    // gates: G[256,1024] = iw[256,256] @ (W_ih + W_hh)^T   32m x 64n tiles, 2x4 micro
    int bid = blockIdx.x;
    int m0 = (bid & 7) * 32, n0 = (bid >> 3) * 64;
    float (*aT)[32] = (float(*)[32])smem;             // aT[kk][m]  [64][32]
    float (*bS)[64] = (float(*)[64])(smem + 2048);    // bS[kk][n]  [64][64]
    int t = threadIdx.x;
    int tm = t & 15, tn = t >> 4;
    float acc[2][4] = {};
    for (int kt = 0; kt < 4; ++kt) {
        int k0 = kt * 64;
        {   // stage A: 32 rows x 16 float4
            int row = t >> 3;
            #pragma unroll
            for (int r = 0; r < 2; ++r) {
                int kq = 2 * (t & 7) + r;
                float4 av = *(const float4*)&iw[(m0 + row) * HID + k0 + 4 * kq];
                aT[4 * kq + 0][row] = av.x; aT[4 * kq + 1][row] = av.y;
                aT[4 * kq + 2][row] = av.z; aT[4 * kq + 3][row] = av.w;
            }
        }
        {   // stage B: 64 rows x 16 float4 (wih+whh)
            int row = t >> 2;
            #pragma unroll
            for (int r = 0; r < 4; ++r) {
                int kq = 4 * (t & 3) + r;
                float4 b1 = *(const float4*)&wih[(n0 + row) * HID + k0 + 4 * kq];
                float4 b2 = *(const float4*)&whh[(n0 + row) * HID + k0 + 4 * kq];
                bS[4 * kq + 0][row] = b1.x + b2.x; bS[4 * kq + 1][row] = b1.y + b2.y;
                bS[4 * kq + 2][row] = b1.z + b2.z; bS[4 * kq + 3][row] = b1.w + b2.w;
            }
        }
        __syncthreads();
        #pragma unroll 8
        for (int kk = 0; kk < 64; ++kk) {
            float2 a2 = *(const float2*)&aT[kk][2 * tm];
            float4 b4 = *(const float4*)&bS[kk][4 * tn];
            float a[2] = {a2.x, a2.y};
            float b[4] = {b4.x, b4.y, b4.z, b4.w};
            #pragma unroll
            for (int i = 0; i < 2; ++i)
                #pragma unroll
                for (int j = 0; j < 4; ++j)
                    acc[i][j] = fmaf(a[i], b[j], acc[i][j]);
        }
        __syncthreads();
    }
    #pragma unroll
    for (int i = 0; i < 2; ++i) {
        float4 o = make_float4(acc[i][0], acc[i][1], acc[i][2], acc[i][3]);
        *(float4*)&G[(m0 + 2 * tm + i) * 1024 + n0 + 4 * tn] = o;
    }
}

// ---- K2 fused: LSTM nonlinearity (blocks 0..255) + dinv LUT (256..295)
__device__ __forceinline__ float sig_f(float x)  { return 1.f / (1.f + __expf(-x)); }
__device__ __forceinline__ float tanh_f(float x) { return 1.f - 2.f / (1.f + __expf(2.f * x)); }

__global__ __launch_bounds__(256)
void k_wev_dinv(const float* __restrict__ G, const float* __restrict__ iw,
                const float* __restrict__ b_ih, const float* __restrict__ b_hh,
                float* __restrict__ Wev, const int* __restrict__ cursor,
                float* __restrict__ dinv) {
    if (blockIdx.x >= 256) {
        int v = (blockIdx.x - 256) * 256 + threadIdx.x;
        if (v < N_NODES) dinv[v] = rsqrtf((float)(cursor[v] + 1));
        return;
    }
    int r = blockIdx.x;
    int j = threadIdx.x;
    float gi = G[r * 1024 + 0   + j] + b_ih[0   + j] + b_hh[0   + j];
    float gf = G[r * 1024 + 256 + j] + b_ih[256 + j] + b_hh[256 + j];
    float gg = G[r * 1024 + 512 + j] + b_ih[512 + j] + b_hh[512 + j];
    float go = G[r * 1024 + 768 + j] + b_ih[768 + j] + b_hh[768 + j];
    float c  = sig_f(gf) * iw[r * HID + j] + sig_f(gi) * tanh_f(gg);
    Wev[r * HID + j] = sig_f(go) * tanh_f(c);
}

// ---- K3 fused: Wc GEMM -> WcT bf16 (blocks 0..128) + aggregation (129..2628)
__global__ __launch_bounds__(256)
void k_wc_agg(const unsigned* __restrict__ xb, const int* __restrict__ bucket,
              const int* __restrict__ cursor, const float* __restrict__ dinv,
              unsigned* __restrict__ yb, float* __restrict__ rs,
              const float* __restrict__ Wp, const float* __restrict__ bp,
              const float* __restrict__ Wev, unsigned* __restrict__ wct,
              float* __restrict__ bc) {
    __shared__ float arow[HID];
    if (blockIdx.x < 129) {
        int a = blockIdx.x;  // 0..128 (128 = bias row)
        int j = threadIdx.x;
        const float* srcRow = (a < IN_DIM) ? &Wp[a * HID] : bp;
        arow[j] = srcRow[j];
        __syncthreads();
        float acc = 0.f;
        #pragma unroll 4
        for (int k = 0; k < HID; ++k)
            acc = fmaf(arow[k], Wev[k * HID + j], acc);
        if (a < IN_DIM)
            ((unsigned short*)wct)[j * IN_DIM + a] = (unsigned short)bf16rne(acc);
        else
            bc[j] = acc;
        return;
    }
    int wv   = threadIdx.x >> 6;
    int lane = threadIdx.x & 63;
    int v = (blockIdx.x - 129) * 4 + wv;   // < 10000
    int cntv = cursor[v];
    float dv = dinv[v];
    int cnt = cntv > CAP ? CAP : cntv;
    unsigned self = xb[v * 64 + lane];
    union { unsigned u; float f; } c0, c1;
    c0.u = self << 16; c1.u = self & 0xFFFF0000u;
    float acc0 = dv * c0.f, acc1 = dv * c1.f;
    float wsum = dv;
    const int4* bkt4 = (const int4*)&bucket[v * CAP];
    int j = 0;
    for (; j + 4 <= cnt; j += 4) {
        int4 s = bkt4[j >> 2];
        float w0 = dinv[s.x], w1 = dinv[s.y], w2 = dinv[s.z], w3 = dinv[s.w];
        unsigned r0 = xb[s.x * 64 + lane];
        unsigned r1 = xb[s.y * 64 + lane];
        unsigned r2 = xb[s.z * 64 + lane];
        unsigned r3 = xb[s.w * 64 + lane];
        union { unsigned u; float f; } a0, a1;
        a0.u = r0 << 16; a1.u = r0 & 0xFFFF0000u;
        acc0 = fmaf(w0, a0.f, acc0); acc1 = fmaf(w0, a1.f, acc1);
        a0.u = r1 << 16; a1.u = r1 & 0xFFFF0000u;
        acc0 = fmaf(w1, a0.f, acc0); acc1 = fmaf(w1, a1.f, acc1);
        a0.u = r2 << 16; a1.u = r2 & 0xFFFF0000u;
        acc0 = fmaf(w2, a0.f, acc0); acc1 = fmaf(w2, a1.f, acc1);
        a0.u = r3 << 16; a1.u = r3 & 0xFFFF0000u;
        acc0 = fmaf(w3, a0.f, acc0); acc1 = fmaf(w3, a1.f, acc1);
        wsum += w0 + w1 + w2 + w3;
    }
    for (; j < cnt; ++j) {
        int s = ((const int*)bkt4)[j];
        float w = dinv[s];
        unsigned r = xb[s * 64 + lane];
        union { unsigned u; float f; } a0, a1;
        a0.u = r << 16; a1.u = r & 0xFFFF0000u;
        acc0 = fmaf(w, a0.f, acc0); acc1 = fmaf(w, a1.f, acc1);
        wsum += w;
    }
    yb[v * 64 + lane] = bf16rne(dv * acc0) | (bf16rne(dv * acc1) << 16);
    if (lane == 0) rs[v] = dv * wsum;
}

// ---- K4: out[10000,256] = yb[10000,128] @ WcT^T + rs*bc + b_gcn   (bf16 MFMA)
// 625 blocks x 4 waves; block = 16-row m-tile; wave w covers n-tiles w,w+4,w+8,w+12.
// A[m=lane&15][k=q*8+j], B[n=lane&15][k=q*8+j], D: col=lane&15, row=q*4+reg.
__global__ __launch_bounds__(256)
void k_out(const unsigned* __restrict__ yb, const unsigned* __restrict__ wct,
           const float* __restrict__ bc, const float* __restrict__ rs,
           const float* __restrict__ b_gcn, float* __restrict__ out) {
    int m0 = blockIdx.x * 16;
    int w = threadIdx.x >> 6, lane = threadIdx.x & 63;
    int q = lane >> 4, ln = lane & 15;
    const int4* yb4  = (const int4*)yb;   // row stride 16 int4
    const int4* wct4 = (const int4*)wct;
    union { int4 v; frag_ab f; } a[4];
    #pragma unroll
    for (int kc = 0; kc < 4; ++kc)
        a[kc].v = yb4[(m0 + ln) * 16 + kc * 4 + q];
    float rsv[4];
    #pragma unroll
    for (int r = 0; r < 4; ++r) rsv[r] = rs[m0 + q * 4 + r];
    #pragma unroll
    for (int i = 0; i < 4; ++i) {
        int n0 = (w + 4 * i) * 16;
        union { int4 v; frag_ab f; } b[4];
        #pragma unroll
        for (int kc = 0; kc < 4; ++kc)
            b[kc].v = wct4[(n0 + ln) * 16 + kc * 4 + q];
        frag_cd acc = {0.f, 0.f, 0.f, 0.f};
        #pragma unroll
        for (int kc = 0; kc < 4; ++kc)
            acc = __builtin_amdgcn_mfma_f32_16x16x32_bf16(a[kc].f, b[kc].f, acc, 0, 0, 0);
        int n = n0 + ln;
        float bcv = bc[n], bgv = b_gcn[n];
        #pragma unroll
        for (int r = 0; r < 4; ++r) {
            int m = m0 + q * 4 + r;
            out[m * HID + n] = acc[r] + rsv[r] * bcv + bgv;
        }
    }
}

extern "C" void kernel_launch(void* const* d_in, const int* in_sizes, int n_in,
                              void* d_out, int out_size, void* d_ws, size_t ws_size,
                              hipStream_t stream) {
    const float* x     = (const float*)d_in[0];
    const int*   ei    = (const int*)d_in[1];
    const float* Wp    = (const float*)d_in[2];
    const float* bp    = (const float*)d_in[3];
    const float* W_ih  = (const float*)d_in[4];
    const float* W_hh  = (const float*)d_in[5];
    const float* b_ih  = (const float*)d_in[6];
    const float* b_hh  = (const float*)d_in[7];
    const float* iw    = (const float*)d_in[8];
    const float* b_gcn = (const float*)d_in[9];
    float* out = (float*)d_out;

    char* ws = (char*)d_ws;
    unsigned* yb     = (unsigned*)(ws + 0);
    float*    G      = (float*)   (ws + 2560000);
    float*    Wev    = (float*)   (ws + 3608576);
    unsigned* wct    = (unsigned*)(ws + 3870720);
    float*    bc     = (float*)   (ws + 3936256);
    float*    rs     = (float*)   (ws + 3937280);
    unsigned* xb     = (unsigned*)(ws + 3977280);
    int*      cursor = (int*)     (ws + 6537280);
    float*    dinv   = (float*)   (ws + 6577280);
    int*      bucket = (int*)     (ws + 6617280);

    hipMemsetAsync(cursor, 0, N_NODES * sizeof(int), stream);

    // K1: gates GEMM + bucket fill + x->bf16 (wide, 640 blocks)
    k_prep<<<NB_GATES + NB_FILL + NB_XCVT, 256, 0, stream>>>(
        ei, cursor, bucket, iw, W_ih, W_hh, G, x, xb);
    // K2: LSTM nonlinearity + dinv LUT
    k_wev_dinv<<<256 + 40, 256, 0, stream>>>(G, iw, b_ih, b_hh, Wev, cursor, dinv);
    // K3: WcT bf16 GEMM + aggregation
    k_wc_agg<<<129 + 2500, 256, 0, stream>>>(xb, bucket, cursor, dinv, yb, rs, Wp, bp, Wev, wct, bc);
    // K4: final GEMM via bf16 MFMA + epilogue
    k_out<<<625, 256, 0, stream>>>(yb, wct, bc, rs, b_gcn, out);
}